// Round 1
// baseline (96.878 us; speedup 1.0000x reference)
//
#include <hip/hip_runtime.h>

// KaolinRenderer: coverage-mask rasterizer.
// Output = repeat(mask[B,H,W], 3) — the z-buffer in the reference is dead code
// for the returned value, so we only compute the inside-test OR over faces.
//
// BIT-EXACTNESS IS CRITICAL: mask is binary, threshold 2e-2. Faces with
// w-clamped vertices (|ndc| ~1e8) have catastrophically-cancelling edge
// functions whose sign is rounding-determined. We therefore mirror the numpy
// reference's float32 op order exactly and disable FMA contraction.

#pragma clang fp contract(off)

#define HW      256
#define BATCH   2
#define VCOUNT  4096
#define FCOUNT  4096
#define CHUNK_F 512

__global__ __launch_bounds__(256)
void vert_kernel(const float* __restrict__ verts,
                 const float* __restrict__ R,
                 const float* __restrict__ T,
                 float2* __restrict__ ndc)   // [B*V] (x,y only; z unused)
{
#pragma clang fp contract(off)
    int gid = blockIdx.x * blockDim.x + threadIdx.x;
    if (gid >= BATCH * VCOUNT) return;
    int b = gid / VCOUNT;

    // f = 1/tan(radians(60)/2) computed in double by Python then cast to f32.
    const float fproj = 1.7320508075688772f;   // rounds to 0x3FDDB3D7 like numpy

    const float* Rb = R + b * 9;
    const float* Tb = T + b * 3;

    // t_i = -((Rt[i][0]*T0 + Rt[i][1]*T1) + Rt[i][2]*T2), Rt[i][j] = R[j][i]
    // (sequential accumulation like np.einsum)
    float t0 = -((Rb[0*3+0]*Tb[0] + Rb[1*3+0]*Tb[1]) + Rb[2*3+0]*Tb[2]);
    float t1 = -((Rb[0*3+1]*Tb[0] + Rb[1*3+1]*Tb[1]) + Rb[2*3+1]*Tb[2]);
    float t2 = -((Rb[0*3+2]*Tb[0] + Rb[1*3+2]*Tb[1]) + Rb[2*3+2]*Tb[2]);

    // VP = proj @ w2c. Only rows 0 (x), 1 (y), 3 (w) are needed.
    // Row0: f * w2c[0][k]; Row1: f * w2c[1][k]; Row3: -w2c[2][k].
    // (zeros in proj contribute exact +/-0 terms — no rounding effect)
    float VP00 = fproj * Rb[0*3+0], VP01 = fproj * Rb[1*3+0],
          VP02 = fproj * Rb[2*3+0], VP03 = fproj * t0;
    float VP10 = fproj * Rb[0*3+1], VP11 = fproj * Rb[1*3+1],
          VP12 = fproj * Rb[2*3+1], VP13 = fproj * t1;
    float VP30 = -Rb[0*3+2], VP31 = -Rb[1*3+2],
          VP32 = -Rb[2*3+2], VP33 = -t2;

    const float* vv = verts + (size_t)gid * 3;
    float vx = vv[0], vy = vv[1], vz = vv[2];

    // cam_j = ((vx*VPj0 + vy*VPj1) + vz*VPj2) + 1*VPj3  (sequential)
    float cx = ((vx*VP00 + vy*VP01) + vz*VP02) + VP03;
    float cy = ((vx*VP10 + vy*VP11) + vz*VP12) + VP13;
    float cw = ((vx*VP30 + vy*VP31) + vz*VP32) + VP33;

    float w = fmaxf(cw, 1e-8f);
    ndc[gid] = make_float2(cx / w, cy / w);
}

__global__ __launch_bounds__(256)
void raster_kernel(const float2* __restrict__ ndc,
                   const int* __restrict__ faces,
                   float* __restrict__ out)
{
#pragma clang fp contract(off)
    __shared__ float sx0[CHUNK_F], sy0[CHUNK_F];
    __shared__ float sx1[CHUNK_F], sy1[CHUNK_F];
    __shared__ float sx2[CHUNK_F], sy2[CHUNK_F];
    __shared__ float sd01x[CHUNK_F], sd01y[CHUNK_F];
    __shared__ float sd12x[CHUNK_F], sd12y[CHUNK_F];
    __shared__ float sd20x[CHUNK_F], sd20y[CHUNK_F];

    int b    = blockIdx.y;
    int tile = blockIdx.x;                       // 16x16 tiles over 256x256
    int tx = (tile & 15) << 4;
    int ty = (tile >> 4) << 4;
    int px_i = tx + (threadIdx.x & 15);
    int py_i = ty + (threadIdx.x >> 4);

    // Same formula as reference: ((i + 0.5)/W)*2 - 1, all exact-rounded f32 ops
    float px = (((float)px_i + 0.5f) / 256.0f) * 2.0f - 1.0f;
    float py = (((float)py_i + 0.5f) / 256.0f) * 2.0f - 1.0f;

    const float2* nb = ndc + b * VCOUNT;
    const int*    fb = faces + b * FCOUNT * 3;

    bool covered = false;

    for (int c0 = 0; c0 < FCOUNT; c0 += CHUNK_F) {
        // Stage chunk: per-face coords + edge diffs (diffs computed once per
        // face, exactly like the reference's broadcasted (x1-x0) etc.)
        for (int t = threadIdx.x; t < CHUNK_F; t += 256) {
            int fi = c0 + t;
            int i0 = fb[fi*3 + 0], i1 = fb[fi*3 + 1], i2 = fb[fi*3 + 2];
            float2 p0 = nb[i0], p1 = nb[i1], p2 = nb[i2];
            sx0[t] = p0.x; sy0[t] = p0.y;
            sx1[t] = p1.x; sy1[t] = p1.y;
            sx2[t] = p2.x; sy2[t] = p2.y;
            sd01x[t] = p1.x - p0.x; sd01y[t] = p1.y - p0.y;
            sd12x[t] = p2.x - p1.x; sd12y[t] = p2.y - p1.y;
            sd20x[t] = p0.x - p2.x; sd20y[t] = p0.y - p2.y;
        }
        __syncthreads();

        if (!covered) {
            for (int f = 0; f < CHUNK_F; ++f) {
                // e = (x1-x0)*(py-y0) - (y1-y0)*(px-x0): mul, mul, sub — no FMA
                float e0 = sd01x[f] * (py - sy0[f]) - sd01y[f] * (px - sx0[f]);
                float e1 = sd12x[f] * (py - sy1[f]) - sd12y[f] * (px - sx1[f]);
                float e2 = sd20x[f] * (py - sy2[f]) - sd20y[f] * (px - sx2[f]);
                // all-nonneg OR all-nonpos (no NaNs present; +/-0 both pass)
                float mn = fminf(fminf(e0, e1), e2);
                float mx = fmaxf(fmaxf(e0, e1), e2);
                covered = covered || (mn >= 0.0f) || (mx <= 0.0f);
            }
        }

        // Block-uniform early exit; doubles as the barrier before next stage.
        if (__syncthreads_and(covered ? 1 : 0)) break;
    }

    float val = covered ? 1.0f : 0.0f;
    size_t o = ((size_t)(b * HW + py_i) * HW + px_i) * 3;
    out[o + 0] = val;
    out[o + 1] = val;
    out[o + 2] = val;
}

extern "C" void kernel_launch(void* const* d_in, const int* in_sizes, int n_in,
                              void* d_out, int out_size, void* d_ws, size_t ws_size,
                              hipStream_t stream) {
    const float* verts = (const float*)d_in[0];   // [2,4096,3] f32
    const int*   faces = (const int*)d_in[1];     // [2,4096,3] i32
    const float* R     = (const float*)d_in[2];   // [2,3,3]    f32
    const float* T     = (const float*)d_in[3];   // [2,3]      f32
    float*       out   = (float*)d_out;           // [2,256,256,3] f32

    float2* ndc = (float2*)d_ws;                  // [2*4096] float2 = 64 KiB

    int nv = BATCH * VCOUNT;
    vert_kernel<<<(nv + 255) / 256, 256, 0, stream>>>(verts, R, T, ndc);

    dim3 grid(256, BATCH);
    raster_kernel<<<grid, 256, 0, stream>>>(ndc, faces, out);
}

// Round 2
// 65.783 us; speedup vs baseline: 1.4727x; 1.4727x over previous
//
#include <hip/hip_runtime.h>

// KaolinRenderer: coverage-mask rasterizer.
// Output = repeat(mask[B,H,W], 3) — the z-buffer in the reference is dead code
// for the returned value, so we only compute the inside-test OR over faces.
//
// BIT-EXACTNESS IS CRITICAL: mask is binary, threshold 2e-2. Faces with
// w-clamped vertices (|ndc| ~1e8) have catastrophically-cancelling edge
// functions whose sign is rounding-determined. We mirror the numpy reference's
// float32 op order exactly and disable FMA contraction. Skipping faces once
// `covered` is true is safe (sticky OR); changing the per-face arithmetic is not.
//
// R2: (1) per-wave early break every 8 faces via __all(covered) — chunk-level
// exit alone forced testing up to 512 faces past coverage; (2) LDS packed as
// 3x float4 per face -> ds_read_b128 x3 instead of ds_read_b32 x12.

#pragma clang fp contract(off)

#define HW      256
#define BATCH   2
#define VCOUNT  4096
#define FCOUNT  4096
#define CHUNK_F 512

__global__ __launch_bounds__(256)
void vert_kernel(const float* __restrict__ verts,
                 const float* __restrict__ R,
                 const float* __restrict__ T,
                 float2* __restrict__ ndc)   // [B*V] (x,y only; z unused)
{
#pragma clang fp contract(off)
    int gid = blockIdx.x * blockDim.x + threadIdx.x;
    if (gid >= BATCH * VCOUNT) return;
    int b = gid / VCOUNT;

    const float fproj = 1.7320508075688772f;   // 1/tan(30deg), f64->f32 like numpy

    const float* Rb = R + b * 9;
    const float* Tb = T + b * 3;

    // t_i = -((Rt[i][0]*T0 + Rt[i][1]*T1) + Rt[i][2]*T2), Rt[i][j] = R[j][i]
    float t0 = -((Rb[0*3+0]*Tb[0] + Rb[1*3+0]*Tb[1]) + Rb[2*3+0]*Tb[2]);
    float t1 = -((Rb[0*3+1]*Tb[0] + Rb[1*3+1]*Tb[1]) + Rb[2*3+1]*Tb[2]);
    float t2 = -((Rb[0*3+2]*Tb[0] + Rb[1*3+2]*Tb[1]) + Rb[2*3+2]*Tb[2]);

    // VP rows 0 (x), 1 (y), 3 (w) only.
    float VP00 = fproj * Rb[0*3+0], VP01 = fproj * Rb[1*3+0],
          VP02 = fproj * Rb[2*3+0], VP03 = fproj * t0;
    float VP10 = fproj * Rb[0*3+1], VP11 = fproj * Rb[1*3+1],
          VP12 = fproj * Rb[2*3+1], VP13 = fproj * t1;
    float VP30 = -Rb[0*3+2], VP31 = -Rb[1*3+2],
          VP32 = -Rb[2*3+2], VP33 = -t2;

    const float* vv = verts + (size_t)gid * 3;
    float vx = vv[0], vy = vv[1], vz = vv[2];

    float cx = ((vx*VP00 + vy*VP01) + vz*VP02) + VP03;
    float cy = ((vx*VP10 + vy*VP11) + vz*VP12) + VP13;
    float cw = ((vx*VP30 + vy*VP31) + vz*VP32) + VP33;

    float w = fmaxf(cw, 1e-8f);
    ndc[gid] = make_float2(cx / w, cy / w);
}

__global__ __launch_bounds__(256)
void raster_kernel(const float2* __restrict__ ndc,
                   const int* __restrict__ faces,
                   float* __restrict__ out)
{
#pragma clang fp contract(off)
    // Per-face packed data, 3 float4 each:
    //  [0] = (x0, y0, x1, y1)
    //  [1] = (x2, y2, d01x, d01y)
    //  [2] = (d12x, d12y, d20x, d20y)
    __shared__ float4 sf[CHUNK_F * 3];   // 24 KiB

    int b    = blockIdx.y;
    int tile = blockIdx.x;                       // 16x16 tiles over 256x256
    int px_i = ((tile & 15) << 4) + (threadIdx.x & 15);
    int py_i = ((tile >> 4) << 4) + (threadIdx.x >> 4);

    // Same formula as reference: ((i + 0.5)/W)*2 - 1
    float px = (((float)px_i + 0.5f) / 256.0f) * 2.0f - 1.0f;
    float py = (((float)py_i + 0.5f) / 256.0f) * 2.0f - 1.0f;

    const float2* nb = ndc + b * VCOUNT;
    const int*    fb = faces + b * FCOUNT * 3;

    bool covered = false;

    for (int c0 = 0; c0 < FCOUNT; c0 += CHUNK_F) {
        // Stage chunk (2 faces per thread). Diffs computed once per face,
        // exactly like the reference's broadcasted (x1-x0) etc.
        for (int t = threadIdx.x; t < CHUNK_F; t += 256) {
            const int* fp = fb + (size_t)(c0 + t) * 3;
            int i0 = fp[0], i1 = fp[1], i2 = fp[2];
            float2 p0 = nb[i0], p1 = nb[i1], p2 = nb[i2];
            sf[t*3 + 0] = make_float4(p0.x, p0.y, p1.x, p1.y);
            sf[t*3 + 1] = make_float4(p2.x, p2.y, p1.x - p0.x, p1.y - p0.y);
            sf[t*3 + 2] = make_float4(p2.x - p1.x, p2.y - p1.y,
                                      p0.x - p2.x, p0.y - p2.y);
        }
        __syncthreads();

        // Test faces; whole-wave break every 8 faces once this wave's 16x4
        // pixel strip is fully covered (safe: covered is a sticky OR).
        for (int f8 = 0; f8 < CHUNK_F; f8 += 8) {
            if (__all((int)covered)) break;
#pragma unroll
            for (int k = 0; k < 8; ++k) {
                int f = f8 + k;
                float4 a = sf[f*3 + 0];
                float4 c = sf[f*3 + 1];
                float4 d = sf[f*3 + 2];
                // e = (x1-x0)*(py-y0) - (y1-y0)*(px-x0): mul, mul, sub — no FMA
                float e0 = c.z * (py - a.y) - c.w * (px - a.x);
                float e1 = d.x * (py - a.w) - d.y * (px - a.z);
                float e2 = d.z * (py - c.y) - d.w * (px - c.x);
                float mn = fminf(fminf(e0, e1), e2);
                float mx = fmaxf(fmaxf(e0, e1), e2);
                covered = covered || (mn >= 0.0f) || (mx <= 0.0f);
            }
        }

        // Block-uniform early exit; doubles as the barrier before next stage.
        if (__syncthreads_and((int)covered)) break;
    }

    float val = covered ? 1.0f : 0.0f;
    size_t o = ((size_t)(b * HW + py_i) * HW + px_i) * 3;
    out[o + 0] = val;
    out[o + 1] = val;
    out[o + 2] = val;
}

extern "C" void kernel_launch(void* const* d_in, const int* in_sizes, int n_in,
                              void* d_out, int out_size, void* d_ws, size_t ws_size,
                              hipStream_t stream) {
    const float* verts = (const float*)d_in[0];   // [2,4096,3] f32
    const int*   faces = (const int*)d_in[1];     // [2,4096,3] i32
    const float* R     = (const float*)d_in[2];   // [2,3,3]    f32
    const float* T     = (const float*)d_in[3];   // [2,3]      f32
    float*       out   = (float*)d_out;           // [2,256,256,3] f32

    float2* ndc = (float2*)d_ws;                  // [2*4096] float2 = 64 KiB

    int nv = BATCH * VCOUNT;
    vert_kernel<<<(nv + 255) / 256, 256, 0, stream>>>(verts, R, T, ndc);

    dim3 grid(256, BATCH);
    raster_kernel<<<grid, 256, 0, stream>>>(ndc, faces, out);
}

// Round 3
// 65.668 us; speedup vs baseline: 1.4753x; 1.0018x over previous
//
#include <hip/hip_runtime.h>

// KaolinRenderer: coverage-mask rasterizer.
// Output = repeat(mask[B,H,W], 3) — the reference z-buffer is dead code.
//
// BIT-EXACTNESS IS CRITICAL: mask is binary, threshold 2e-2. Faces with
// w-clamped vertices (|ndc| ~1e8) have catastrophically-cancelling edge
// functions whose sign is rounding-determined. We mirror the numpy reference's
// float32 op order exactly and disable FMA contraction. Skipping faces once
// `covered` is true is safe (sticky OR); changing per-face arithmetic is not.
//
// R3: face_pack prepass computes per-face packed edge data once (recomputing
// vertex NDC with the identical instruction sequence — bit-exact), raster
// streams it from global via wave-broadcast loads with no LDS/barriers and a
// per-wave __all(covered) break every 8 faces. vert_kernel eliminated.

#pragma clang fp contract(off)

#define HW      256
#define BATCH   2
#define VCOUNT  4096
#define FCOUNT  4096

// Per-face packed data, 3 float4 each:
//  [0] = (x0, y0, x1, y1)
//  [1] = (x2, y2, d01x, d01y)
//  [2] = (d12x, d12y, d20x, d20y)

__global__ __launch_bounds__(256)
void face_pack_kernel(const float* __restrict__ verts,
                      const int* __restrict__ faces,
                      const float* __restrict__ R,
                      const float* __restrict__ T,
                      float4* __restrict__ fpack)   // [B*F*3]
{
#pragma clang fp contract(off)
    int gid = blockIdx.x * blockDim.x + threadIdx.x;
    if (gid >= BATCH * FCOUNT) return;
    int b = gid / FCOUNT;

    const float fproj = 1.7320508075688772f;   // 1/tan(30deg), f64->f32 like numpy

    const float* Rb = R + b * 9;
    const float* Tb = T + b * 3;

    // t_i = -((Rt[i][0]*T0 + Rt[i][1]*T1) + Rt[i][2]*T2), Rt[i][j] = R[j][i]
    float t0 = -((Rb[0*3+0]*Tb[0] + Rb[1*3+0]*Tb[1]) + Rb[2*3+0]*Tb[2]);
    float t1 = -((Rb[0*3+1]*Tb[0] + Rb[1*3+1]*Tb[1]) + Rb[2*3+1]*Tb[2]);
    float t2 = -((Rb[0*3+2]*Tb[0] + Rb[1*3+2]*Tb[1]) + Rb[2*3+2]*Tb[2]);

    // VP rows 0 (x), 1 (y), 3 (w) only.
    float VP00 = fproj * Rb[0*3+0], VP01 = fproj * Rb[1*3+0],
          VP02 = fproj * Rb[2*3+0], VP03 = fproj * t0;
    float VP10 = fproj * Rb[0*3+1], VP11 = fproj * Rb[1*3+1],
          VP12 = fproj * Rb[2*3+1], VP13 = fproj * t1;
    float VP30 = -Rb[0*3+2], VP31 = -Rb[1*3+2],
          VP32 = -Rb[2*3+2], VP33 = -t2;

    const int* fp = faces + (size_t)gid * 3;
    float xs[3], ys[3];
#pragma unroll
    for (int j = 0; j < 3; ++j) {
        const float* vv = verts + ((size_t)b * VCOUNT + fp[j]) * 3;
        float vx = vv[0], vy = vv[1], vz = vv[2];
        // Identical op sequence to the reference einsum (sequential adds),
        // contract off => bit-identical NDC for every reference to a vertex.
        float cx = ((vx*VP00 + vy*VP01) + vz*VP02) + VP03;
        float cy = ((vx*VP10 + vy*VP11) + vz*VP12) + VP13;
        float cw = ((vx*VP30 + vy*VP31) + vz*VP32) + VP33;
        float w = fmaxf(cw, 1e-8f);
        xs[j] = cx / w;
        ys[j] = cy / w;
    }

    float4* o = fpack + (size_t)gid * 3;
    o[0] = make_float4(xs[0], ys[0], xs[1], ys[1]);
    o[1] = make_float4(xs[2], ys[2], xs[1] - xs[0], ys[1] - ys[0]);
    o[2] = make_float4(xs[2] - xs[1], ys[2] - ys[1], xs[0] - xs[2], ys[0] - ys[2]);
}

__global__ __launch_bounds__(256)
void raster_kernel(const float4* __restrict__ fpack,
                   float* __restrict__ out)
{
#pragma clang fp contract(off)
    int b    = blockIdx.y;
    int tile = blockIdx.x;                       // 16x16 tiles over 256x256
    int px_i = ((tile & 15) << 4) + (threadIdx.x & 15);
    int py_i = ((tile >> 4) << 4) + (threadIdx.x >> 4);

    // Same formula as reference: ((i + 0.5)/W)*2 - 1
    float px = (((float)px_i + 0.5f) / 256.0f) * 2.0f - 1.0f;
    float py = (((float)py_i + 0.5f) / 256.0f) * 2.0f - 1.0f;

    const float4* fb = fpack + (size_t)b * FCOUNT * 3;

    bool covered = false;

    // Stream faces; all 64 lanes of a wave read the same face data (broadcast,
    // single transaction, L1/L2-hit — the 192 KB/batch stream is L2-resident).
    // Whole-wave break every 8 faces once this wave's 16x4 strip is covered.
    for (int f8 = 0; f8 < FCOUNT; f8 += 8) {
        if (__all((int)covered)) break;
#pragma unroll
        for (int k = 0; k < 8; ++k) {
            const float4* q = fb + (size_t)(f8 + k) * 3;
            float4 a = q[0];
            float4 c = q[1];
            float4 d = q[2];
            // e = (x1-x0)*(py-y0) - (y1-y0)*(px-x0): mul, mul, sub — no FMA
            float e0 = c.z * (py - a.y) - c.w * (px - a.x);
            float e1 = d.x * (py - a.w) - d.y * (px - a.z);
            float e2 = d.z * (py - c.y) - d.w * (px - c.x);
            float mn = fminf(fminf(e0, e1), e2);
            float mx = fmaxf(fmaxf(e0, e1), e2);
            covered = covered || (mn >= 0.0f) || (mx <= 0.0f);
        }
    }

    float val = covered ? 1.0f : 0.0f;
    size_t o = ((size_t)(b * HW + py_i) * HW + px_i) * 3;
    out[o + 0] = val;
    out[o + 1] = val;
    out[o + 2] = val;
}

extern "C" void kernel_launch(void* const* d_in, const int* in_sizes, int n_in,
                              void* d_out, int out_size, void* d_ws, size_t ws_size,
                              hipStream_t stream) {
    const float* verts = (const float*)d_in[0];   // [2,4096,3] f32
    const int*   faces = (const int*)d_in[1];     // [2,4096,3] i32
    const float* R     = (const float*)d_in[2];   // [2,3,3]    f32
    const float* T     = (const float*)d_in[3];   // [2,3]      f32
    float*       out   = (float*)d_out;           // [2,256,256,3] f32

    float4* fpack = (float4*)d_ws;                // [2*4096*3] float4 = 384 KiB

    int nf = BATCH * FCOUNT;
    face_pack_kernel<<<(nf + 255) / 256, 256, 0, stream>>>(verts, faces, R, T, fpack);

    dim3 grid(256, BATCH);
    raster_kernel<<<grid, 256, 0, stream>>>(fpack, out);
}

// Round 4
// 63.641 us; speedup vs baseline: 1.5223x; 1.0318x over previous
//
#include <hip/hip_runtime.h>

// KaolinRenderer: coverage-mask rasterizer.
// Output = repeat(mask[B,H,W], 3) — the reference z-buffer is dead code.
//
// BIT-EXACTNESS IS CRITICAL: mask is binary, threshold 2e-2. Faces with
// w-clamped vertices (|ndc| ~1e8) have catastrophically-cancelling edge
// functions whose sign is rounding-determined. We mirror the numpy reference's
// float32 op order exactly and disable FMA contraction. Skipping faces once
// `covered` is true is safe (sticky OR); changing per-face arithmetic is not.
//
// R4: per-wave conservative half-plane interval cull. e_i(p)=A*py+B*px+C is
// affine; over a wave's 16x4 strip rect we bound it at the rect corners. Face
// skippable iff some edge certifies "computed e < 0 everywhere" AND some edge
// certifies "computed e > 0 everywhere" (kills both sign branches). err_i =
// 2^-16 * (|dx|*(1+|ya|) + |dy|*(1+|xa|)) covers the rounding gap between the
// corner evaluation and the reference's per-pixel formula with ~22x margin
// (combined bound ~2^-20 * envelope). Unlike bbox culls this has no
// sliver/collinear failure mode and fails safe (no-cull -> full bit-exact
// test). 64 lanes cull 64 faces in parallel; __ballot compacts survivors.

#pragma clang fp contract(off)

#define HW      256
#define BATCH   2
#define VCOUNT  4096
#define FCOUNT  4096
#define CULL_EPS 1.52587890625e-05f   // 2^-16

// fpack: per-face exact-test data, 3 float4 each:
//  [0] = (x0, y0, x1, y1)
//  [1] = (x2, y2, d01x, d01y)
//  [2] = (d12x, d12y, d20x, d20y)
// fcull: per-face cull records, 3 float4 each (one per edge):
//  (A, B, C, err) with e(p) ~= A*py + B*px + C

__global__ __launch_bounds__(256)
void face_pack_kernel(const float* __restrict__ verts,
                      const int* __restrict__ faces,
                      const float* __restrict__ R,
                      const float* __restrict__ T,
                      float4* __restrict__ fpack,
                      float4* __restrict__ fcull)
{
#pragma clang fp contract(off)
    int gid = blockIdx.x * blockDim.x + threadIdx.x;
    if (gid >= BATCH * FCOUNT) return;
    int b = gid / FCOUNT;

    const float fproj = 1.7320508075688772f;   // 1/tan(30deg), f64->f32 like numpy

    const float* Rb = R + b * 9;
    const float* Tb = T + b * 3;

    // t_i = -((Rt[i][0]*T0 + Rt[i][1]*T1) + Rt[i][2]*T2), Rt[i][j] = R[j][i]
    float t0 = -((Rb[0*3+0]*Tb[0] + Rb[1*3+0]*Tb[1]) + Rb[2*3+0]*Tb[2]);
    float t1 = -((Rb[0*3+1]*Tb[0] + Rb[1*3+1]*Tb[1]) + Rb[2*3+1]*Tb[2]);
    float t2 = -((Rb[0*3+2]*Tb[0] + Rb[1*3+2]*Tb[1]) + Rb[2*3+2]*Tb[2]);

    // VP rows 0 (x), 1 (y), 3 (w) only.
    float VP00 = fproj * Rb[0*3+0], VP01 = fproj * Rb[1*3+0],
          VP02 = fproj * Rb[2*3+0], VP03 = fproj * t0;
    float VP10 = fproj * Rb[0*3+1], VP11 = fproj * Rb[1*3+1],
          VP12 = fproj * Rb[2*3+1], VP13 = fproj * t1;
    float VP30 = -Rb[0*3+2], VP31 = -Rb[1*3+2],
          VP32 = -Rb[2*3+2], VP33 = -t2;

    const int* fp = faces + (size_t)gid * 3;
    float xs[3], ys[3];
#pragma unroll
    for (int j = 0; j < 3; ++j) {
        const float* vv = verts + ((size_t)b * VCOUNT + fp[j]) * 3;
        float vx = vv[0], vy = vv[1], vz = vv[2];
        // Identical op sequence to the reference einsum (sequential adds),
        // contract off => bit-identical NDC for every reference to a vertex.
        float cx = ((vx*VP00 + vy*VP01) + vz*VP02) + VP03;
        float cy = ((vx*VP10 + vy*VP11) + vz*VP12) + VP13;
        float cw = ((vx*VP30 + vy*VP31) + vz*VP32) + VP33;
        float w = fmaxf(cw, 1e-8f);
        xs[j] = cx / w;
        ys[j] = cy / w;
    }

    float d01x = xs[1] - xs[0], d01y = ys[1] - ys[0];
    float d12x = xs[2] - xs[1], d12y = ys[2] - ys[1];
    float d20x = xs[0] - xs[2], d20y = ys[0] - ys[2];

    float4* o = fpack + (size_t)gid * 3;
    o[0] = make_float4(xs[0], ys[0], xs[1], ys[1]);
    o[1] = make_float4(xs[2], ys[2], d01x, d01y);
    o[2] = make_float4(d12x, d12y, d20x, d20y);

    // Cull records. e0 = d01x*(py-y0) - d01y*(px-x0) => A=d01x, B=-d01y,
    // C = d01y*x0 - d01x*y0. err envelope uses |py|<=1, |px|<=1 on screen.
    float4* c = fcull + (size_t)gid * 3;
    c[0] = make_float4(d01x, -d01y, d01y*xs[0] - d01x*ys[0],
                       CULL_EPS * (fabsf(d01x)*(1.0f+fabsf(ys[0]))
                                 + fabsf(d01y)*(1.0f+fabsf(xs[0]))));
    c[1] = make_float4(d12x, -d12y, d12y*xs[1] - d12x*ys[1],
                       CULL_EPS * (fabsf(d12x)*(1.0f+fabsf(ys[1]))
                                 + fabsf(d12y)*(1.0f+fabsf(xs[1]))));
    c[2] = make_float4(d20x, -d20y, d20y*xs[2] - d20x*ys[2],
                       CULL_EPS * (fabsf(d20x)*(1.0f+fabsf(ys[2]))
                                 + fabsf(d20y)*(1.0f+fabsf(xs[2]))));
}

__device__ __forceinline__ void cull_edge(float4 c, float pxlo, float pxhi,
                                          float pylo, float pyhi,
                                          bool& killneg, bool& killpos)
{
    // hi/lo bound the reference-computed e over the rect (margin folded in err).
    float yh = (c.x > 0.0f) ? pyhi : pylo;
    float yl = (c.x > 0.0f) ? pylo : pyhi;
    float xh = (c.y > 0.0f) ? pxhi : pxlo;
    float xl = (c.y > 0.0f) ? pxlo : pxhi;
    float hi = c.x * yh + c.y * xh + c.z;
    float lo = c.x * yl + c.y * xl + c.z;
    killneg = killneg || (hi < -c.w);   // computed e < 0 on whole rect
    killpos = killpos || (lo >  c.w);   // computed e > 0 on whole rect
}

__global__ __launch_bounds__(256)
void raster_kernel(const float4* __restrict__ fpack,
                   const float4* __restrict__ fcull,
                   float* __restrict__ out)
{
#pragma clang fp contract(off)
    int b    = blockIdx.y;
    int tile = blockIdx.x;                       // 16x16 tiles over 256x256
    int tx = (tile & 15) << 4;
    int ty = (tile >> 4) << 4;
    int px_i = tx + (threadIdx.x & 15);
    int py_i = ty + (threadIdx.x >> 4);

    // Same formula as reference: ((i + 0.5)/W)*2 - 1
    float px = (((float)px_i + 0.5f) / 256.0f) * 2.0f - 1.0f;
    float py = (((float)py_i + 0.5f) / 256.0f) * 2.0f - 1.0f;

    // This wave's 16x4 strip rect (pixel-coord formula is monotone in index,
    // so corner pixels bound all lane coords).
    int wave = threadIdx.x >> 6;
    int lane = threadIdx.x & 63;
    int ry   = ty + wave * 4;
    float pxlo = (((float)tx        + 0.5f) / 256.0f) * 2.0f - 1.0f;
    float pxhi = (((float)(tx + 15) + 0.5f) / 256.0f) * 2.0f - 1.0f;
    float pylo = (((float)ry        + 0.5f) / 256.0f) * 2.0f - 1.0f;
    float pyhi = (((float)(ry + 3)  + 0.5f) / 256.0f) * 2.0f - 1.0f;

    const float4* fb = fpack + (size_t)b * FCOUNT * 3;
    const float4* cb = fcull + (size_t)b * FCOUNT * 3;

    bool covered = false;

    for (int g = 0; g < FCOUNT; g += 64) {
        if (__all((int)covered)) break;

        // Phase 1: each lane culls one face against the wave's strip rect.
        const float4* cr = cb + (size_t)(g + lane) * 3;
        float4 c0 = cr[0], c1 = cr[1], c2 = cr[2];
        bool killneg = false, killpos = false;
        cull_edge(c0, pxlo, pxhi, pylo, pyhi, killneg, killpos);
        cull_edge(c1, pxlo, pxhi, pylo, pyhi, killneg, killpos);
        cull_edge(c2, pxlo, pxhi, pylo, pyhi, killneg, killpos);
        bool skip = killneg && killpos;

        // Phase 2: test survivors only (wave-uniform mask, broadcast loads).
        unsigned long long m = __ballot((int)!skip);
        while (m) {
            if (__all((int)covered)) break;
            int k = __ffsll(m) - 1;
            m &= m - 1;
            const float4* q = fb + (size_t)(g + k) * 3;
            float4 a = q[0];
            float4 c = q[1];
            float4 d = q[2];
            // e = (x1-x0)*(py-y0) - (y1-y0)*(px-x0): mul, mul, sub — no FMA
            float e0 = c.z * (py - a.y) - c.w * (px - a.x);
            float e1 = d.x * (py - a.w) - d.y * (px - a.z);
            float e2 = d.z * (py - c.y) - d.w * (px - c.x);
            float mn = fminf(fminf(e0, e1), e2);
            float mx = fmaxf(fmaxf(e0, e1), e2);
            covered = covered || (mn >= 0.0f) || (mx <= 0.0f);
        }
    }

    float val = covered ? 1.0f : 0.0f;
    size_t o = ((size_t)(b * HW + py_i) * HW + px_i) * 3;
    out[o + 0] = val;
    out[o + 1] = val;
    out[o + 2] = val;
}

extern "C" void kernel_launch(void* const* d_in, const int* in_sizes, int n_in,
                              void* d_out, int out_size, void* d_ws, size_t ws_size,
                              hipStream_t stream) {
    const float* verts = (const float*)d_in[0];   // [2,4096,3] f32
    const int*   faces = (const int*)d_in[1];     // [2,4096,3] i32
    const float* R     = (const float*)d_in[2];   // [2,3,3]    f32
    const float* T     = (const float*)d_in[3];   // [2,3]      f32
    float*       out   = (float*)d_out;           // [2,256,256,3] f32

    float4* fpack = (float4*)d_ws;                       // 384 KiB
    float4* fcull = fpack + (size_t)BATCH * FCOUNT * 3;  // 384 KiB

    int nf = BATCH * FCOUNT;
    face_pack_kernel<<<(nf + 255) / 256, 256, 0, stream>>>(verts, faces, R, T,
                                                           fpack, fcull);

    dim3 grid(256, BATCH);
    raster_kernel<<<grid, 256, 0, stream>>>(fpack, fcull, out);
}